// Round 13
// baseline (1028.175 us; speedup 1.0000x reference)
//
#include <hip/hip_runtime.h>

#define B_N 4096
#define C_N 128
#define E_N 10

#define NM3 165
#define NM2 45
#define NMT 219           // dense m: deg1 0..8, deg2 9..53, deg3 54..218
#define NB  2             // nodes (list slots) per thread, contiguous pair
#define TSTRIDE 224       // float4 stride per (e,c) table (3584 B)

// Usym float-offsets (relative to usym base in ws)
#define OFF_S3 0          // [165][23]
#define OFF_V3 3795       // [165][3][15]
#define OFF_S2 11220      // [45][3]
#define OFF_V2 11355      // [45][12]
#define USYM_FLOATS 11895

// ws byte offsets
#define WS_CNT    0
#define WS_LIST   64
#define WS_USYM   (64 + B_N * E_N * 4)            // 163904
#define WS_TABLES 212992                           // 1024-aligned
// tables bytes: 1280 * 224 * 16 = 4,587,520

__device__ __forceinline__ void unrank3(int m, int& I, int& J, int& K) {
    int n = 0;
    for (int i = 0; i < 9; ++i)
        for (int j = i; j < 9; ++j)
            for (int k = j; k < 9; ++k) {
                if (n == m) { I = i; J = j; K = k; return; }
                ++n;
            }
}
__device__ __forceinline__ void unrank2(int m, int& I, int& J) {
    int n = 0;
    for (int i = 0; i < 9; ++i)
        for (int j = i; j < 9; ++j) {
            if (n == m) { I = i; J = j; return; }
            ++n;
        }
}

// ---------------------------------------------------------------------------
// Kernel 1: bucket nodes by element (y one-hot over E=10).
// ---------------------------------------------------------------------------
__global__ __launch_bounds__(256) void build_lists_kernel(
    const float* __restrict__ y, int* __restrict__ cnt, int* __restrict__ list)
{
    int b = blockIdx.x * 256 + threadIdx.x;
    if (b >= B_N) return;
    const float* yb = y + (size_t)b * E_N;
    int e = 0;
#pragma unroll
    for (int j = 1; j < E_N; ++j) e = (yb[j] > 0.5f) ? j : e;
    int pos = atomicAdd(&cnt[e], 1);
    list[e * B_N + pos] = b;
}

// ---------------------------------------------------------------------------
// Kernel 2: symmetrize U tensors into monomial basis (e,c-independent).
// (R11-proven separate pass; fusing into build_tables cost +25 us in R12.)
// ---------------------------------------------------------------------------
__global__ __launch_bounds__(256) void sym_u_kernel(
    const float* __restrict__ U3s, const float* __restrict__ U2s,
    const float* __restrict__ U3v, const float* __restrict__ U2v,
    float* __restrict__ us)
{
    int t = blockIdx.x * 256 + threadIdx.x;
    if (t < 3795) {                      // S3: [165][23]
        int m = t / 23, kk = t - m * 23;
        int i, j, k; unrank3(m, i, j, k);
        float sc = (i == k) ? (1.f / 6.f) : ((i == j || j == k) ? 0.5f : 1.f);
#define U3S(a,b,cc) U3s[(((a)*9+(b))*9+(cc))*23 + kk]
        float v = U3S(i,j,k) + U3S(i,k,j) + U3S(j,i,k) + U3S(j,k,i) + U3S(k,i,j) + U3S(k,j,i);
        us[OFF_S3 + m * 23 + kk] = v * sc;
    } else if (t < 11220) {              // V3: [165][3][15]
        int r = t - 3795;
        int m = r / 45, q = r - m * 45;
        int a = q / 15, kk = q - a * 15;
        int i, j, k; unrank3(m, i, j, k);
        float sc = (i == k) ? (1.f / 6.f) : ((i == j || j == k) ? 0.5f : 1.f);
#define U3V(p,b,cc) U3v[((((a)*9+(p))*9+(b))*9+(cc))*15 + kk]
        float v = U3V(i,j,k) + U3V(i,k,j) + U3V(j,i,k) + U3V(j,k,i) + U3V(k,i,j) + U3V(k,j,i);
        us[OFF_V3 + m * 45 + a * 15 + kk] = v * sc;
    } else if (t < 11355) {              // S2: [45][3]
        int r = t - 11220;
        int m = r / 3, kk = r - m * 3;
        int i, j; unrank2(m, i, j);
        float sc = (i == j) ? 0.5f : 1.f;
        us[OFF_S2 + m * 3 + kk] =
            (U2s[(i * 9 + j) * 3 + kk] + U2s[(j * 9 + i) * 3 + kk]) * sc;
    } else if (t < USYM_FLOATS) {        // V2: [45][12]
        int r = t - 11355;
        int m = r / 12, q = r - m * 12;
        int a = q / 4, kk = q - a * 4;
        int i, j; unrank2(m, i, j);
        float sc = (i == j) ? 0.5f : 1.f;
        us[OFF_V2 + m * 12 + a * 4 + kk] =
            (U2v[((a * 9 + i) * 9 + j) * 4 + kk] + U2v[((a * 9 + j) * 9 + i) * 4 + kk]) * sc;
    }
}

// ---------------------------------------------------------------------------
// Kernel 3: build per-(e,c) monomial coefficient tables in GLOBAL ws.
// Table[(e*128+c)*224 + m] = float4(s, v0, v1, v2); m dense: 0..8 deg1,
// 9..53 deg2, 54..218 deg3 (lexicographic triangular = main walk order).
// ---------------------------------------------------------------------------
__global__ __launch_bounds__(256) void build_tables_kernel(
    const float* __restrict__ usym,
    const float* __restrict__ U1s, const float* __restrict__ U1v,
    const float* __restrict__ W1s, const float* __restrict__ W2s, const float* __restrict__ W3s,
    const float* __restrict__ W1v, const float* __restrict__ W2v, const float* __restrict__ W3v,
    float* __restrict__ tables)
{
    const int c = blockIdx.x;   // 0..127
    const int e = blockIdx.y;   // 0..9
    const int m = threadIdx.x;
    if (m >= NMT) return;

    float4 t;
    if (m < 9) {
        const int i = m;
        t.x = U1s[i]      * W1s[e * C_N + c];
        t.y = U1v[i]      * W1v[e * C_N + c];
        t.z = U1v[9 + i]  * W1v[e * C_N + c];
        t.w = U1v[18 + i] * W1v[e * C_N + c];
    } else if (m < 9 + NM2) {
        const int mm = m - 9;
        float s = 0.f;
#pragma unroll
        for (int k = 0; k < 3; ++k)
            s = fmaf(usym[OFF_S2 + mm * 3 + k], W2s[(e * 3 + k) * C_N + c], s);
        t.x = s;
        float tv[3];
#pragma unroll
        for (int a = 0; a < 3; ++a) {
            float sv = 0.f;
#pragma unroll
            for (int k = 0; k < 4; ++k)
                sv = fmaf(usym[OFF_V2 + mm * 12 + a * 4 + k], W2v[(e * 4 + k) * C_N + c], sv);
            tv[a] = sv;
        }
        t.y = tv[0]; t.z = tv[1]; t.w = tv[2];
    } else {
        const int mm = m - (9 + NM2);
        float s = 0.f;
#pragma unroll
        for (int k = 0; k < 23; ++k)
            s = fmaf(usym[OFF_S3 + mm * 23 + k], W3s[(e * 23 + k) * C_N + c], s);
        t.x = s;
        float tv[3];
#pragma unroll
        for (int a = 0; a < 3; ++a) {
            float sv = 0.f;
#pragma unroll
            for (int k = 0; k < 15; ++k)
                sv = fmaf(usym[OFF_V3 + mm * 45 + a * 15 + k], W3v[(e * 15 + k) * C_N + c], sv);
            tv[a] = sv;
        }
        t.y = tv[0]; t.z = tv[1]; t.w = tv[2];
    }
    ((float4*)tables)[(size_t)(e * C_N + c) * TSTRIDE + m] = t;
}

// ---------------------------------------------------------------------------
// Kernel 4: main contraction. LDS-staged table (float2 SoA, ds_read_b64
// same-address broadcasts) + NB=2 nodes per thread: the wave reads the table
// ONCE per 2 nodes -> LDS instructions per node halve (438 -> 219) and wave
// count halves. Per-CU arithmetic: ~20 waves x 438 b64 x ~6cyc = 53K cyc LDS
// vs 24K VALU -> LDS-bound ~22us. NB=2 is safe HERE because the spill
// failures (R6/R7/R10) were SMEM-lane or cap-64 artifacts; LDS lane at NB=1
// ran VGPR=100 clean; (256,2) cap 256 gives headroom.
// ---------------------------------------------------------------------------
__global__ __launch_bounds__(256, 2) void sc_main_kernel(
    const float* __restrict__ x,
    const int* __restrict__ cnt, const int* __restrict__ list,
    const float* __restrict__ tables,
    float* __restrict__ out)
{
    const int c     = blockIdx.x;   // 0..127
    const int e     = blockIdx.y;   // 0..9
    const int chunk = blockIdx.z;   // 0..1 (512 slots per block; 2*512=1024)

    const int n = cnt[e];
    if (chunk * 512 >= n) return;   // block-uniform exit (pre-barrier)

    __shared__ float2 Txy[NMT];
    __shared__ float2 Tzw[NMT];
    const int tid = threadIdx.x;

    if (tid < NMT) {
        float4 t = ((const float4*)tables)[(size_t)(e * C_N + c) * TSTRIDE + tid];
        Txy[tid] = make_float2(t.x, t.y);
        Tzw[tid] = make_float2(t.z, t.w);
    }
    __syncthreads();

    const int base2 = chunk * 512 + tid * NB;
    if (base2 >= n) return;         // no barriers after this point

    int bis[NB];
    float xr[NB][9];
#pragma unroll
    for (int nb = 0; nb < NB; ++nb) {
        int idx = base2 + nb;
        int cl  = idx < n ? idx : n - 1;
        int bi  = list[e * B_N + cl];
        bis[nb] = bi;
        const float* xp = x + ((size_t)bi * C_N + c) * 9;
#pragma unroll
        for (int q = 0; q < 9; ++q) xr[nb][q] = xp[q];
    }

    float ax[NB], ay[NB], az[NB], aw[NB];
#pragma unroll
    for (int nb = 0; nb < NB; ++nb) { ax[nb] = ay[nb] = az[nb] = aw[nb] = 0.f; }

    // ---- degree 1: m = 0..8 ----
#pragma unroll
    for (int i = 0; i < 9; ++i) {
        float2 a = Txy[i];
        float2 bb = Tzw[i];
#pragma unroll
        for (int nb = 0; nb < NB; ++nb) {
            float q = xr[nb][i];
            ax[nb] = fmaf(a.x, q, ax[nb]);
            ay[nb] = fmaf(a.y, q, ay[nb]);
            az[nb] = fmaf(bb.x, q, az[nb]);
            aw[nb] = fmaf(bb.y, q, aw[nb]);
        }
    }

    // ---- degree 2: m = 9..53, ascending pair order ----
    int m2 = 9;
#pragma unroll
    for (int i = 0; i < 9; ++i) {
#pragma unroll
        for (int j = i; j < 9; ++j) {
            float2 a = Txy[m2];
            float2 bb = Tzw[m2];
#pragma unroll
            for (int nb = 0; nb < NB; ++nb) {
                float p = xr[nb][i] * xr[nb][j];
                ax[nb] = fmaf(a.x, p, ax[nb]);
                ay[nb] = fmaf(a.y, p, ay[nb]);
                az[nb] = fmaf(bb.x, p, az[nb]);
                aw[nb] = fmaf(bb.y, p, aw[nb]);
            }
            ++m2;
        }
    }

    // ---- degree 3: m = 54..218, ascending lexicographic order ----
    int m3 = 54;
#pragma unroll
    for (int i = 0; i < 9; ++i) {
#pragma unroll
        for (int j = i; j < 9; ++j) {
            float pp[NB];
#pragma unroll
            for (int nb = 0; nb < NB; ++nb) pp[nb] = xr[nb][i] * xr[nb][j];
#pragma unroll
            for (int k = j; k < 9; ++k) {
                float2 a = Txy[m3];
                float2 bb = Tzw[m3];
#pragma unroll
                for (int nb = 0; nb < NB; ++nb) {
                    float q = pp[nb] * xr[nb][k];
                    ax[nb] = fmaf(a.x, q, ax[nb]);
                    ay[nb] = fmaf(a.y, q, ay[nb]);
                    az[nb] = fmaf(bb.x, q, az[nb]);
                    aw[nb] = fmaf(bb.y, q, aw[nb]);
                }
                ++m3;
            }
        }
    }

#pragma unroll
    for (int nb = 0; nb < NB; ++nb) {
        if (base2 + nb < n) {
            float* o = out + (size_t)bis[nb] * 512;
            o[c] = ax[nb];
            o[128 + c * 3 + 0] = ay[nb];
            o[128 + c * 3 + 1] = az[nb];
            o[128 + c * 3 + 2] = aw[nb];
        }
    }
}

// ---------------------------------------------------------------------------
extern "C" void kernel_launch(void* const* d_in, const int* in_sizes, int n_in,
                              void* d_out, int out_size, void* d_ws, size_t ws_size,
                              hipStream_t stream) {
    const float* x   = (const float*)d_in[0];
    const float* y   = (const float*)d_in[1];
    const float* U1s = (const float*)d_in[2];
    const float* U2s = (const float*)d_in[3];
    const float* U3s = (const float*)d_in[4];
    const float* W1s = (const float*)d_in[5];
    const float* W2s = (const float*)d_in[6];
    const float* W3s = (const float*)d_in[7];
    const float* U1v = (const float*)d_in[8];
    const float* U2v = (const float*)d_in[9];
    const float* U3v = (const float*)d_in[10];
    const float* W1v = (const float*)d_in[11];
    const float* W2v = (const float*)d_in[12];
    const float* W3v = (const float*)d_in[13];
    float* out = (float*)d_out;

    int*   cnt    = (int*)((char*)d_ws + WS_CNT);
    int*   list   = (int*)((char*)d_ws + WS_LIST);
    float* usym   = (float*)((char*)d_ws + WS_USYM);
    float* tables = (float*)((char*)d_ws + WS_TABLES);

    hipMemsetAsync(d_ws, 0, 64, stream);
    build_lists_kernel<<<dim3(16), dim3(256), 0, stream>>>(y, cnt, list);
    sym_u_kernel<<<dim3((USYM_FLOATS + 255) / 256), dim3(256), 0, stream>>>(
        U3s, U2s, U3v, U2v, usym);
    build_tables_kernel<<<dim3(128, E_N), dim3(256), 0, stream>>>(
        usym, U1s, U1v, W1s, W2s, W3s, W1v, W2v, W3v, tables);
    sc_main_kernel<<<dim3(128, E_N, 2), dim3(256), 0, stream>>>(
        x, cnt, list, tables, out);
}

// Round 14
// 79.612 us; speedup vs baseline: 12.9149x; 12.9149x over previous
//
#include <hip/hip_runtime.h>

#define B_N 4096
#define C_N 128
#define E_N 10

#define NM3 165
#define NM2 45
#define NMT 219           // dense m: deg1 0..8, deg2 9..53, deg3 54..218
#define MSPLIT 110        // m < MSPLIT read via SMEM; m >= MSPLIT via LDS
#define NLDS (NMT - MSPLIT)   // 109 staged monomials
#define TSTRIDE 224       // float4 stride per (e,c) table (3584 B)

// Usym float-offsets (relative to usym base in ws)
#define OFF_S3 0          // [165][23]
#define OFF_V3 3795       // [165][3][15]
#define OFF_S2 11220      // [45][3]
#define OFF_V2 11355      // [45][12]
#define USYM_FLOATS 11895

// ws byte offsets
#define WS_CNT    0
#define WS_LIST   64
#define WS_USYM   (64 + B_N * E_N * 4)            // 163904
#define WS_TABLES 212992                           // 1024-aligned
// tables bytes: 1280 * 224 * 16 = 4,587,520

__device__ __forceinline__ void unrank3(int m, int& I, int& J, int& K) {
    int n = 0;
    for (int i = 0; i < 9; ++i)
        for (int j = i; j < 9; ++j)
            for (int k = j; k < 9; ++k) {
                if (n == m) { I = i; J = j; K = k; return; }
                ++n;
            }
}
__device__ __forceinline__ void unrank2(int m, int& I, int& J) {
    int n = 0;
    for (int i = 0; i < 9; ++i)
        for (int j = i; j < 9; ++j) {
            if (n == m) { I = i; J = j; return; }
            ++n;
        }
}

// ---------------------------------------------------------------------------
// Kernel 1: bucket nodes by element (y one-hot over E=10).
// ---------------------------------------------------------------------------
__global__ __launch_bounds__(256) void build_lists_kernel(
    const float* __restrict__ y, int* __restrict__ cnt, int* __restrict__ list)
{
    int b = blockIdx.x * 256 + threadIdx.x;
    if (b >= B_N) return;
    const float* yb = y + (size_t)b * E_N;
    int e = 0;
#pragma unroll
    for (int j = 1; j < E_N; ++j) e = (yb[j] > 0.5f) ? j : e;
    int pos = atomicAdd(&cnt[e], 1);
    list[e * B_N + pos] = b;
}

// ---------------------------------------------------------------------------
// Kernel 2: symmetrize U tensors into monomial basis (e,c-independent).
// ---------------------------------------------------------------------------
__global__ __launch_bounds__(256) void sym_u_kernel(
    const float* __restrict__ U3s, const float* __restrict__ U2s,
    const float* __restrict__ U3v, const float* __restrict__ U2v,
    float* __restrict__ us)
{
    int t = blockIdx.x * 256 + threadIdx.x;
    if (t < 3795) {                      // S3: [165][23]
        int m = t / 23, kk = t - m * 23;
        int i, j, k; unrank3(m, i, j, k);
        float sc = (i == k) ? (1.f / 6.f) : ((i == j || j == k) ? 0.5f : 1.f);
#define U3S(a,b,cc) U3s[(((a)*9+(b))*9+(cc))*23 + kk]
        float v = U3S(i,j,k) + U3S(i,k,j) + U3S(j,i,k) + U3S(j,k,i) + U3S(k,i,j) + U3S(k,j,i);
        us[OFF_S3 + m * 23 + kk] = v * sc;
    } else if (t < 11220) {              // V3: [165][3][15]
        int r = t - 3795;
        int m = r / 45, q = r - m * 45;
        int a = q / 15, kk = q - a * 15;
        int i, j, k; unrank3(m, i, j, k);
        float sc = (i == k) ? (1.f / 6.f) : ((i == j || j == k) ? 0.5f : 1.f);
#define U3V(p,b,cc) U3v[((((a)*9+(p))*9+(b))*9+(cc))*15 + kk]
        float v = U3V(i,j,k) + U3V(i,k,j) + U3V(j,i,k) + U3V(j,k,i) + U3V(k,i,j) + U3V(k,j,i);
        us[OFF_V3 + m * 45 + a * 15 + kk] = v * sc;
    } else if (t < 11355) {              // S2: [45][3]
        int r = t - 11220;
        int m = r / 3, kk = r - m * 3;
        int i, j; unrank2(m, i, j);
        float sc = (i == j) ? 0.5f : 1.f;
        us[OFF_S2 + m * 3 + kk] =
            (U2s[(i * 9 + j) * 3 + kk] + U2s[(j * 9 + i) * 3 + kk]) * sc;
    } else if (t < USYM_FLOATS) {        // V2: [45][12]
        int r = t - 11355;
        int m = r / 12, q = r - m * 12;
        int a = q / 4, kk = q - a * 4;
        int i, j; unrank2(m, i, j);
        float sc = (i == j) ? 0.5f : 1.f;
        us[OFF_V2 + m * 12 + a * 4 + kk] =
            (U2v[((a * 9 + i) * 9 + j) * 4 + kk] + U2v[((a * 9 + j) * 9 + i) * 4 + kk]) * sc;
    }
}

// ---------------------------------------------------------------------------
// Kernel 3: build per-(e,c) monomial coefficient tables in GLOBAL ws.
// Table[(e*128+c)*224 + m] = float4(s, v0, v1, v2); m dense: 0..8 deg1,
// 9..53 deg2, 54..218 deg3 (lexicographic triangular = main walk order).
// ---------------------------------------------------------------------------
__global__ __launch_bounds__(256) void build_tables_kernel(
    const float* __restrict__ usym,
    const float* __restrict__ U1s, const float* __restrict__ U1v,
    const float* __restrict__ W1s, const float* __restrict__ W2s, const float* __restrict__ W3s,
    const float* __restrict__ W1v, const float* __restrict__ W2v, const float* __restrict__ W3v,
    float* __restrict__ tables)
{
    const int c = blockIdx.x;   // 0..127
    const int e = blockIdx.y;   // 0..9
    const int m = threadIdx.x;
    if (m >= NMT) return;

    float4 t;
    if (m < 9) {
        const int i = m;
        t.x = U1s[i]      * W1s[e * C_N + c];
        t.y = U1v[i]      * W1v[e * C_N + c];
        t.z = U1v[9 + i]  * W1v[e * C_N + c];
        t.w = U1v[18 + i] * W1v[e * C_N + c];
    } else if (m < 9 + NM2) {
        const int mm = m - 9;
        float s = 0.f;
#pragma unroll
        for (int k = 0; k < 3; ++k)
            s = fmaf(usym[OFF_S2 + mm * 3 + k], W2s[(e * 3 + k) * C_N + c], s);
        t.x = s;
        float tv[3];
#pragma unroll
        for (int a = 0; a < 3; ++a) {
            float sv = 0.f;
#pragma unroll
            for (int k = 0; k < 4; ++k)
                sv = fmaf(usym[OFF_V2 + mm * 12 + a * 4 + k], W2v[(e * 4 + k) * C_N + c], sv);
            tv[a] = sv;
        }
        t.y = tv[0]; t.z = tv[1]; t.w = tv[2];
    } else {
        const int mm = m - (9 + NM2);
        float s = 0.f;
#pragma unroll
        for (int k = 0; k < 23; ++k)
            s = fmaf(usym[OFF_S3 + mm * 23 + k], W3s[(e * 23 + k) * C_N + c], s);
        t.x = s;
        float tv[3];
#pragma unroll
        for (int a = 0; a < 3; ++a) {
            float sv = 0.f;
#pragma unroll
            for (int k = 0; k < 15; ++k)
                sv = fmaf(usym[OFF_V3 + mm * 45 + a * 15 + k], W3v[(e * 15 + k) * C_N + c], sv);
            tv[a] = sv;
        }
        t.y = tv[0]; t.z = tv[1]; t.w = tv[2];
    }
    ((float4*)tables)[(size_t)(e * C_N + c) * TSTRIDE + m] = t;
}

// ---------------------------------------------------------------------------
// Kernel 4: main contraction — DUAL-PIPE coefficient fetch, NB=1 (the only
// non-spilling width). Monomials m=0..109 read via the SMEM lane (R9-proven:
// block-uniform pointer, ascending walk -> merged s_load into SGPRs);
// monomials m=110..218 staged once into LDS (1.7 KB, b32 SoA, R11-proven
// same-address broadcasts). Each lane alone saturates at ~60 us carrying all
// 219; halving each stream and overlapping waves in different phases puts
// both pipes to work concurrently.
// ---------------------------------------------------------------------------
__global__ __launch_bounds__(256) void sc_main_kernel(
    const float* __restrict__ x,
    const int* __restrict__ cnt, const int* __restrict__ list,
    const float* __restrict__ tables,
    float* __restrict__ out)
{
    const int c     = blockIdx.x;   // 0..127
    const int e     = blockIdx.y;   // 0..9
    const int chunk = blockIdx.z;   // 0..3

    const int n = cnt[e];
    if (chunk * 256 >= n) return;   // block-uniform exit (pre-barrier)

    __shared__ float Tx[NLDS], Ty[NLDS], Tz[NLDS], Tw[NLDS];
    const int tid = threadIdx.x;

    if (tid < NLDS) {
        float4 t = ((const float4*)tables)[(size_t)(e * C_N + c) * TSTRIDE + MSPLIT + tid];
        Tx[tid] = t.x; Ty[tid] = t.y; Tz[tid] = t.z; Tw[tid] = t.w;
    }
    __syncthreads();

    const int idx = chunk * 256 + tid;
    if (idx >= n) return;           // no barriers after this point
    const int b = list[e * B_N + idx];

    const float4* __restrict__ T =
        (const float4*)tables + (size_t)(e * C_N + c) * TSTRIDE;   // block-uniform

    const float* xp = x + ((size_t)b * C_N + c) * 9;
    float xr[9];
#pragma unroll
    for (int i = 0; i < 9; ++i) xr[i] = xp[i];

    float ax = 0.f, ay = 0.f, az = 0.f, aw = 0.f;

    // ---- degree 1: m = 0..8 (SMEM) ----
#pragma unroll
    for (int i = 0; i < 9; ++i) {
        float4 t = T[i];
        float q = xr[i];
        ax = fmaf(t.x, q, ax);
        ay = fmaf(t.y, q, ay);
        az = fmaf(t.z, q, az);
        aw = fmaf(t.w, q, aw);
    }

    // ---- degree 2: m = 9..53 (SMEM), ascending pair order ----
    int m2 = 9;
#pragma unroll
    for (int i = 0; i < 9; ++i) {
#pragma unroll
        for (int j = i; j < 9; ++j) {
            float4 t = T[m2++];
            float p = xr[i] * xr[j];
            ax = fmaf(t.x, p, ax);
            ay = fmaf(t.y, p, ay);
            az = fmaf(t.z, p, az);
            aw = fmaf(t.w, p, aw);
        }
    }

    // ---- degree 3: m = 54..218 ascending; m<110 SMEM, m>=110 LDS ----
    int m3 = 54;
#pragma unroll
    for (int i = 0; i < 9; ++i) {
#pragma unroll
        for (int j = i; j < 9; ++j) {
            float p = xr[i] * xr[j];
#pragma unroll
            for (int k = j; k < 9; ++k) {
                float q = p * xr[k];
                if (m3 < MSPLIT) {          // compile-time after full unroll
                    float4 t = T[m3];
                    ax = fmaf(t.x, q, ax);
                    ay = fmaf(t.y, q, ay);
                    az = fmaf(t.z, q, az);
                    aw = fmaf(t.w, q, aw);
                } else {
                    int s = m3 - MSPLIT;
                    ax = fmaf(Tx[s], q, ax);
                    ay = fmaf(Ty[s], q, ay);
                    az = fmaf(Tz[s], q, az);
                    aw = fmaf(Tw[s], q, aw);
                }
                ++m3;
            }
        }
    }

    float* o = out + (size_t)b * 512;
    o[c] = ax;
    o[128 + c * 3 + 0] = ay;
    o[128 + c * 3 + 1] = az;
    o[128 + c * 3 + 2] = aw;
}

// ---------------------------------------------------------------------------
extern "C" void kernel_launch(void* const* d_in, const int* in_sizes, int n_in,
                              void* d_out, int out_size, void* d_ws, size_t ws_size,
                              hipStream_t stream) {
    const float* x   = (const float*)d_in[0];
    const float* y   = (const float*)d_in[1];
    const float* U1s = (const float*)d_in[2];
    const float* U2s = (const float*)d_in[3];
    const float* U3s = (const float*)d_in[4];
    const float* W1s = (const float*)d_in[5];
    const float* W2s = (const float*)d_in[6];
    const float* W3s = (const float*)d_in[7];
    const float* U1v = (const float*)d_in[8];
    const float* U2v = (const float*)d_in[9];
    const float* U3v = (const float*)d_in[10];
    const float* W1v = (const float*)d_in[11];
    const float* W2v = (const float*)d_in[12];
    const float* W3v = (const float*)d_in[13];
    float* out = (float*)d_out;

    int*   cnt    = (int*)((char*)d_ws + WS_CNT);
    int*   list   = (int*)((char*)d_ws + WS_LIST);
    float* usym   = (float*)((char*)d_ws + WS_USYM);
    float* tables = (float*)((char*)d_ws + WS_TABLES);

    hipMemsetAsync(d_ws, 0, 64, stream);
    build_lists_kernel<<<dim3(16), dim3(256), 0, stream>>>(y, cnt, list);
    sym_u_kernel<<<dim3((USYM_FLOATS + 255) / 256), dim3(256), 0, stream>>>(
        U3s, U2s, U3v, U2v, usym);
    build_tables_kernel<<<dim3(128, E_N), dim3(256), 0, stream>>>(
        usym, U1s, U1v, W1s, W2s, W3s, W1v, W2v, W3v, tables);
    sc_main_kernel<<<dim3(128, E_N, 4), dim3(256), 0, stream>>>(
        x, cnt, list, tables, out);
}